// Round 1
// 332.771 us; speedup vs baseline: 1.2424x; 1.2424x over previous
//
#include <hip/hip_runtime.h>

#define B_   2
#define S_   2048
#define D_   1024
#define H_   16
#define DK_  64
#define DFF_ 4096
#define NTOK (B_ * S_)   // 4096

#define QSCALE 0.18033688011112042f   // 0.125 * log2(e)

typedef __bf16 bf16x8 __attribute__((ext_vector_type(8)));
typedef __bf16 bf16x4 __attribute__((ext_vector_type(4)));
typedef float  f32x4  __attribute__((ext_vector_type(4)));

#if __has_builtin(__builtin_amdgcn_exp2f)
#define EXP2(x) __builtin_amdgcn_exp2f(x)
#else
#define EXP2(x) exp2f(x)
#endif

// async global->LDS 16B copy. LDS dest is wave-uniform base + lane*16.
__device__ __forceinline__ void ld16(const __bf16* g, __bf16* l) {
  __builtin_amdgcn_global_load_lds(
      (const __attribute__((address_space(1))) void*)g,
      (__attribute__((address_space(3))) void*)l, 16, 0, 0);
}

// raw barrier: NO implicit vmcnt(0) drain (that drain was the 83% stall).
// memory clobber pins all memory ops (ds_read/gload_lds) within their phase.
#define RAW_BAR()     __asm__ __volatile__("s_barrier" ::: "memory")
#define SCHED_FENCE() __builtin_amdgcn_sched_barrier(0)

// ---------------------------------------------------------------------------
// XCD-aware block swizzle for 256-thread 128^2-tile kernels (O-proj splitk).
// ---------------------------------------------------------------------------
__device__ __forceinline__ void xcd_swizzle(int& bx, int& by) {
  const int gx = gridDim.x;
  const int flat = blockIdx.y * gx + blockIdx.x;
  const int x = flat & 7;
  const int n = flat >> 3;
  if (gx == 32) {
    const int px = (x & 1) << 4, py = (x >> 1) << 3;
    const int g = n >> 5, rem = n & 31;
    bx = px + (g << 2) + (rem & 3);
    by = py + (rem >> 2);
  } else {
    const int g = n >> 4, rem = n & 15;
    bx = (g << 2) + (rem & 3);
    by = (x << 2) + (rem >> 2);
  }
}

// XCD swizzle for 256^2-tile kernels. gy==16 in all uses.
// gx==16 (FFN1, 256 wg): XCD chunk = 4 rows x 8 cols.  gx==4 (QKV/FFN2 per z,
// 64 wg): chunk = 2 rows x 4 cols (A 1MB + B 2MB per XCD -> fits 4MB L2).
__device__ __forceinline__ void xcd_swz256(int& bx, int& by) {
  const int gx = gridDim.x;
  const int flat = blockIdx.y * gx + blockIdx.x;
  const int x = flat & 7, n = flat >> 3;
  if (gx == 16) { by = ((x >> 1) << 2) + (n >> 3); bx = ((x & 1) << 3) + (n & 7); }
  else          { by = (x << 1) + (n >> 2);        bx = n & 3; }
}

// ---------------------------------------------------------------------------
// 256^2 8-phase GEMM core (guide T1+T2+T3+T4+T5). BM=BN=256, BK=64, 8 waves
// (2Mx4N), per-wave C = 128x64 = acc[8][4]. LDS = 2 slots x {A,B} x 2 k-halves
// x [256 rows][32 elems] bf16 = 128 KiB (1 block/CU, 2 waves/SIMD).
//
// Swizzle (T2, verified involution): logical byte L = r*64 + k*2 within a
// half-tile; LDS byte = L ^ (((L>>7)&3)<<4)  i.e. chunk c holds logical chunk
// c ^ ((c>>3)&3). Read lanes (l15=row, q4=k-chunk) land 2 lanes/bank (free,
// m136). gload_lds dest stays LINEAR; the global SOURCE is inverse-permuted.
//
// Phase table per iteration (u even; tile u in slot0, u+1 in slot1):
//   ph1: rd u.A0[fr0-3]+u.B0      | stg (u+1).A1            | MM rows 0-3
//   ph2: rd u.A0[fr4-7]           | stg (u+2).B0            | MM rows 4-7
//   ph3: rd u.A1[fr0-3]+u.B1      | stg (u+2).A0            | MM 0-3
//   ph4: rd u.A1[fr4-7]           | stg (u+2).B1 | vmcnt(6) | MM 4-7
//   ph5: rd (u+1).A0[0-3]+B0      | stg (u+2).A1            | MM 0-3
//   ph6: rd (u+1).A0[4-7]         | stg (u+3).B0            | MM 4-7
//   ph7: rd (u+1).A1[0-3]+B1      | stg (u+3).A0            | MM 0-3
//   ph8: rd (u+1).A1[4-7]         | stg (u+3).B1 | vmcnt(6) | MM 4-7
// Every stage is issued strictly after the phase that last reads its region
// (WAR safe via the barrier pair); vmcnt(6)+barrier at ph4/ph8 guarantees
// landing of everything except the 3 newest half-tiles (RAW safe; checked
// for prologue, steady state, and tail). Last iteration (no u+2 stages)
// needs vmcnt(0) at ph4 to cover (u+1).{B0,A0,B1,A1}.
// ---------------------------------------------------------------------------
__device__ __forceinline__ void lda4(bf16x8 (&afr)[4], const __bf16* hb,
                                     int abase, int f0) {
#pragma unroll
  for (int i = 0; i < 4; ++i)
    afr[i] = *(const bf16x8*)(hb + abase + (f0 + i) * 512);
}

__device__ __forceinline__ void ldb4(bf16x8 (&bfr)[4], const __bf16* hb,
                                     int bbase) {
#pragma unroll
  for (int j = 0; j < 4; ++j)
    bfr[j] = *(const bf16x8*)(hb + bbase + j * 512);
}

__device__ __forceinline__ void mm16(f32x4 (&acc)[8][4], const bf16x8 (&afr)[4],
                                     const bf16x8 (&bfr)[4], int r0) {
#pragma unroll
  for (int i = 0; i < 4; ++i)
#pragma unroll
    for (int j = 0; j < 4; ++j)
      acc[r0 + i][j] =
          __builtin_amdgcn_mfma_f32_16x16x32_bf16(afr[i], bfr[j], acc[r0 + i][j], 0, 0, 0);
}

__device__ __forceinline__ void gemm_core_256(
    const __bf16* __restrict__ A, const __bf16* __restrict__ W,
    int ld, int kLen, int rowA0, int rowW0,
    f32x4 (&acc)[8][4], __bf16* Ls)
{
  const int t = threadIdx.x;
  const int lane = t & 63, wv = t >> 6;
  const int wm = wv >> 2, wn = wv & 3;
  const int l15 = lane & 15, q4 = lane >> 4;

  // fragment read offset (elements) within a [256][32] half-tile, swizzled.
  // rbase is 16-aligned so the swizzle bits depend only on l15.
  const int lane_rd = l15 * 32 + ((q4 * 8) ^ (((l15 >> 1) & 3) << 3));
  const int abase = wm * 4096 + lane_rd;   // + fr*512
  const int bbase = wn * 2048 + lane_rd;   // + fc*512

  // stage source permutation: LDS chunk c holds logical chunk c ^ ((c>>3)&3).
  const int sc0 = t ^ ((t >> 3) & 3);      // q=0 chunk; q=1 adds 128 rows
  const __bf16* gA0 = A + (size_t)(rowA0 + (sc0 >> 2)) * ld + (sc0 & 3) * 8;
  const __bf16* gA1 = gA0 + (size_t)128 * ld;
  const __bf16* gW0 = W + (size_t)(rowW0 + (sc0 >> 2)) * ld + (sc0 & 3) * 8;
  const __bf16* gW1 = gW0 + (size_t)128 * ld;
  const int d0 = wv * 512, d1 = 4096 + wv * 512;   // linear LDS dests

#pragma unroll
  for (int i = 0; i < 8; ++i)
#pragma unroll
    for (int j = 0; j < 4; ++j) acc[i][j] = (f32x4){0.f, 0.f, 0.f, 0.f};

#define HBASE(slot, mat, h) (Ls + ((((slot)*2) + (mat)) * 2 + (h)) * 8192)
#define STG_A(tt, h, slot) do { __bf16* _d = HBASE(slot, 0, h);              \
    const int _ko = (tt) * 64 + (h) * 32;                                    \
    ld16(gA0 + _ko, _d + d0); ld16(gA1 + _ko, _d + d1); } while (0)
#define STG_B(tt, h, slot) do { __bf16* _d = HBASE(slot, 1, h);              \
    const int _ko = (tt) * 64 + (h) * 32;                                    \
    ld16(gW0 + _ko, _d + d0); ld16(gW1 + _ko, _d + d1); } while (0)
#define MFMA_PH(r0) do { RAW_BAR(); SCHED_FENCE();                           \
    __builtin_amdgcn_s_setprio(1); mm16(acc, afr, bfr, r0);                  \
    __builtin_amdgcn_s_setprio(0); SCHED_FENCE(); RAW_BAR(); } while (0)

  const int NT = kLen >> 6;
  bf16x8 afr[4], bfr[4];

  // prologue: tile0 (4 halves, oldest) + tile1 {B0,A0,B1} -> vmcnt(6) lands
  // exactly tile0's 8 loads; 3 newest half-tiles stay in flight.
  STG_A(0, 0, 0); STG_A(0, 1, 0); STG_B(0, 0, 0); STG_B(0, 1, 0);
  STG_B(1, 0, 1); STG_A(1, 0, 1); STG_B(1, 1, 1);
  __asm__ __volatile__("s_waitcnt vmcnt(6)" ::: "memory");
  RAW_BAR(); SCHED_FENCE();

  for (int u = 0; u < NT; u += 2) {
    const bool g2 = (u + 2) < NT, g3 = (u + 3) < NT;
    // ph1
    lda4(afr, HBASE(0, 0, 0), abase, 0); ldb4(bfr, HBASE(0, 1, 0), bbase);
    STG_A(u + 1, 1, 1);
    MFMA_PH(0);
    // ph2
    lda4(afr, HBASE(0, 0, 0), abase, 4);
    if (g2) STG_B(u + 2, 0, 0);
    MFMA_PH(4);
    // ph3
    lda4(afr, HBASE(0, 0, 1), abase, 0); ldb4(bfr, HBASE(0, 1, 1), bbase);
    if (g2) STG_A(u + 2, 0, 0);
    MFMA_PH(0);
    // ph4
    lda4(afr, HBASE(0, 0, 1), abase, 4);
    if (g2) {
      STG_B(u + 2, 1, 0);
      __asm__ __volatile__("s_waitcnt vmcnt(6)" ::: "memory");
    } else {
      __asm__ __volatile__("s_waitcnt vmcnt(0)" ::: "memory");  // tail drain
    }
    MFMA_PH(4);
    // ph5
    lda4(afr, HBASE(1, 0, 0), abase, 0); ldb4(bfr, HBASE(1, 1, 0), bbase);
    if (g2) STG_A(u + 2, 1, 0);
    MFMA_PH(0);
    // ph6
    lda4(afr, HBASE(1, 0, 0), abase, 4);
    if (g3) STG_B(u + 3, 0, 1);
    MFMA_PH(4);
    // ph7
    lda4(afr, HBASE(1, 0, 1), abase, 0); ldb4(bfr, HBASE(1, 1, 1), bbase);
    if (g3) STG_A(u + 3, 0, 1);
    MFMA_PH(0);
    // ph8
    lda4(afr, HBASE(1, 0, 1), abase, 4);
    if (g3) STG_B(u + 3, 1, 1);
    __asm__ __volatile__("s_waitcnt vmcnt(6)" ::: "memory");
    MFMA_PH(4);
  }
#undef HBASE
#undef STG_A
#undef STG_B
#undef MFMA_PH
}

// ---------------------------------------------------------------------------
// 128^2 GEMM core (old structure) — kept for O-proj split-K only (8.6 GF;
// a 256^2 tile would leave 3/4 of the CUs idle at N=1024, splitk=2).
// ---------------------------------------------------------------------------
__device__ __forceinline__ void gemm_core_128(
    const __bf16* __restrict__ A, const __bf16* __restrict__ W,
    int ld, int kLen, int rowA0, int rowW0,
    f32x4 (&acc)[4][4], __bf16* As, __bf16* Bs)
{
  const int t    = threadIdx.x;
  const int lane = t & 63;
  const int wv   = t >> 6;
  const int wm   = (wv >> 1) << 6;
  const int wn   = (wv & 1) << 6;
  const int l15  = lane & 15;
  const int q4   = lane >> 4;

#pragma unroll
  for (int i = 0; i < 4; ++i)
#pragma unroll
    for (int j = 0; j < 4; ++j)
      acc[i][j] = (f32x4){0.f, 0.f, 0.f, 0.f};

  const __bf16* gA = A + (size_t)(rowA0 + 32 * wv + l15) * ld + q4 * 8;
  const __bf16* gW = W + (size_t)(rowW0 + 32 * wv + l15) * ld + q4 * 8;
  __bf16* lA = As + wv * 2048;
  __bf16* lB = Bs + wv * 2048;
  const size_t r16 = (size_t)16 * ld;

  const int fbg = (q4 << 7) + (l15 << 3);
  const int ia = (wm >> 4);
  const int ib = (wn >> 4);

  for (int k0 = 0; k0 < kLen; k0 += 64) {
    ld16(gA + k0,            lA);
    ld16(gA + k0 + 32,       lA + 512);
    ld16(gA + k0 + r16,      lA + 1024);
    ld16(gA + k0 + r16 + 32, lA + 1536);
    ld16(gW + k0,            lB);
    ld16(gW + k0 + 32,       lB + 512);
    ld16(gW + k0 + r16,      lB + 1024);
    ld16(gW + k0 + r16 + 32, lB + 1536);
    __syncthreads();
#pragma unroll
    for (int s = 0; s < 2; ++s) {
      bf16x8 af[4], bw[4];
#pragma unroll
      for (int i = 0; i < 4; ++i)
        af[i] = *(const bf16x8*)(As + (ia + i) * 1024 + s * 512 + fbg);
#pragma unroll
      for (int j = 0; j < 4; ++j)
        bw[j] = *(const bf16x8*)(Bs + (ib + j) * 1024 + s * 512 + fbg);
#pragma unroll
      for (int i = 0; i < 4; ++i)
#pragma unroll
        for (int j = 0; j < 4; ++j)
          acc[i][j] = __builtin_amdgcn_mfma_f32_16x16x32_bf16(af[i], bw[j], acc[i][j], 0, 0, 0);
    }
    __syncthreads();
  }
}

// ---------------------------------------------------------------------------
// QKV on the 256^2 core: grid (4,16,3). Q pre-scaled; V stored transposed.
// ---------------------------------------------------------------------------
__global__ __launch_bounds__(512, 2) void gemm_qkv_256(
    const __bf16* __restrict__ xn,
    const __bf16* __restrict__ wqb, const __bf16* __restrict__ wkb,
    const __bf16* __restrict__ wvb,
    __bf16* __restrict__ qo, __bf16* __restrict__ ko, __bf16* __restrict__ vto)
{
  __shared__ __align__(16) __bf16 Ls[65536];   // 128 KiB
  int bx, by; xcd_swz256(bx, by);
  const __bf16* W = blockIdx.z == 0 ? wqb : (blockIdx.z == 1 ? wkb : wvb);
  f32x4 acc[8][4];
  gemm_core_256(xn, W, D_, D_, by * 256, bx * 256, acc, Ls);

  const int t = threadIdx.x, lane = t & 63, wv = t >> 6;
  const int wm = wv >> 2, wn = wv & 3;
  const int l15 = lane & 15, q4 = lane >> 4;
  const int row0 = by * 256 + wm * 128;
  const int col0 = bx * 256 + wn * 64;

  if (blockIdx.z < 2) {
    __bf16* o = blockIdx.z == 0 ? qo : ko;
    const float sc = blockIdx.z == 0 ? QSCALE : 1.0f;
#pragma unroll
    for (int fr = 0; fr < 8; ++fr)
#pragma unroll
      for (int fc = 0; fc < 4; ++fc) {
        const int col = col0 + fc * 16 + l15;
#pragma unroll
        for (int r = 0; r < 4; ++r) {
          const int row = row0 + fr * 16 + q4 * 4 + r;
          o[(size_t)row * D_ + col] = (__bf16)(acc[fr][fc][r] * sc);
        }
      }
  } else {
#pragma unroll
    for (int fr = 0; fr < 8; ++fr)
#pragma unroll
      for (int fc = 0; fc < 4; ++fc) {
        const int tok0 = row0 + fr * 16 + q4 * 4;
        const int c    = col0 + fc * 16 + l15;
        const int b0 = tok0 >> 11, s0 = tok0 & (S_ - 1);
        const int hh = c >> 6, dd = c & (DK_ - 1);
        bf16x4 pk;
#pragma unroll
        for (int r = 0; r < 4; ++r) pk[r] = (__bf16)acc[fr][fc][r];
        *(bf16x4*)&vto[(size_t)((b0 * H_ + hh) * DK_ + dd) * S_ + s0] = pk;
      }
  }
}

// ---------------------------------------------------------------------------
// FFN1 on the 256^2 core: h = relu(A @ W1^T + b1). grid (16,16).
// ---------------------------------------------------------------------------
__global__ __launch_bounds__(512, 2) void gemm_ffn1_256(
    const __bf16* __restrict__ A, const __bf16* __restrict__ W,
    __bf16* __restrict__ outb, const float* __restrict__ bias)
{
  __shared__ __align__(16) __bf16 Ls[65536];
  int bx, by; xcd_swz256(bx, by);
  f32x4 acc[8][4];
  gemm_core_256(A, W, D_, D_, by * 256, bx * 256, acc, Ls);

  const int t = threadIdx.x, lane = t & 63, wv = t >> 6;
  const int wm = wv >> 2, wn = wv & 3;
  const int l15 = lane & 15, q4 = lane >> 4;
  const int row0 = by * 256 + wm * 128;
  const int col0 = bx * 256 + wn * 64;

#pragma unroll
  for (int fr = 0; fr < 8; ++fr)
#pragma unroll
    for (int fc = 0; fc < 4; ++fc) {
      const int col = col0 + fc * 16 + l15;
      const float bs = bias[col];
#pragma unroll
      for (int r = 0; r < 4; ++r) {
        const int row = row0 + fr * 16 + q4 * 4 + r;
        outb[(size_t)row * DFF_ + col] = (__bf16)fmaxf(acc[fr][fc][r] + bs, 0.0f);
      }
    }
}

// ---------------------------------------------------------------------------
// FFN2 on the 256^2 core, split-K=4: grid (4,16,4), bf16 partials contiguous.
// ---------------------------------------------------------------------------
__global__ __launch_bounds__(512, 2) void gemm_ffn2_sk4(
    const __bf16* __restrict__ A, const __bf16* __restrict__ W,
    __bf16* __restrict__ pp)
{
  __shared__ __align__(16) __bf16 Ls[65536];
  int bx, by; xcd_swz256(bx, by);
  const int z = blockIdx.z;
  f32x4 acc[8][4];
  gemm_core_256(A + (size_t)z * 1024, W + (size_t)z * 1024, DFF_, 1024,
                by * 256, bx * 256, acc, Ls);

  const int t = threadIdx.x, lane = t & 63, wv = t >> 6;
  const int wm = wv >> 2, wn = wv & 3;
  const int l15 = lane & 15, q4 = lane >> 4;
  const int row0 = by * 256 + wm * 128;
  const int col0 = bx * 256 + wn * 64;
  __bf16* out = pp + (size_t)z * NTOK * D_;

#pragma unroll
  for (int fr = 0; fr < 8; ++fr)
#pragma unroll
    for (int fc = 0; fc < 4; ++fc) {
      const int col = col0 + fc * 16 + l15;
#pragma unroll
      for (int r = 0; r < 4; ++r) {
        const int row = row0 + fr * 16 + q4 * 4 + r;
        out[(size_t)row * D_ + col] = (__bf16)acc[fr][fc][r];
      }
    }
}

// ---------------------------------------------------------------------------
// O-proj split-K GEMM partials (old 128^2 core). grid (8, 32, 2).
// ---------------------------------------------------------------------------
__global__ __launch_bounds__(256) void gemm_splitk_f32(
    const __bf16* __restrict__ A, const __bf16* __restrict__ W,
    int K, int kPart, float* __restrict__ pp)
{
  __shared__ __align__(16) __bf16 As[128 * 64];
  __shared__ __align__(16) __bf16 Bs[128 * 64];
  int bx, by; xcd_swizzle(bx, by);
  f32x4 acc[4][4];
  const int z = blockIdx.z;
  gemm_core_128(A + (size_t)z * kPart, W + (size_t)z * kPart, K, kPart,
                by * 128, bx * 128, acc, As, Bs);

  const int t = threadIdx.x, lane = t & 63, wv = t >> 6;
  const int wm = (wv >> 1) << 6, wn = (wv & 1) << 6;
  const int l15 = lane & 15, q4 = lane >> 4;
  const int row0 = by * 128 + wm;
  const int col0 = bx * 128 + wn;
  float* out = pp + (size_t)z * NTOK * D_;

#pragma unroll
  for (int i = 0; i < 4; ++i)
#pragma unroll
    for (int j = 0; j < 4; ++j)
#pragma unroll
      for (int r = 0; r < 4; ++r) {
        int row = row0 + 16 * i + q4 * 4 + r;
        int col = col0 + 16 * j + l15;
        out[(size_t)row * D_ + col] = acc[i][j][r];
      }
}

// ---------------------------------------------------------------------------
// O-proj reduce + LN2 fused: x1 = x + p0 + p1; xn2 = LN(x1). 1 block/row.
// ---------------------------------------------------------------------------
__global__ __launch_bounds__(256) void oproj_ln_reduce(
    const float* __restrict__ x, const float* __restrict__ p0,
    const float* __restrict__ p1, const float* __restrict__ alpha,
    const float* __restrict__ bias, float* __restrict__ x1,
    __bf16* __restrict__ xn2)
{
  const int row = blockIdx.x;
  const int t = threadIdx.x;
  const size_t base = (size_t)row * D_;
  float4 v  = ((const float4*)(x  + base))[t];
  const float4 a0 = ((const float4*)(p0 + base))[t];
  const float4 a1 = ((const float4*)(p1 + base))[t];
  v.x += a0.x + a1.x; v.y += a0.y + a1.y;
  v.z += a0.z + a1.z; v.w += a0.w + a1.w;
  ((float4*)(x1 + base))[t] = v;

  float s  = v.x + v.y + v.z + v.w;
  float ss = v.x * v.x + v.y * v.y + v.z * v.z + v.w * v.w;
#pragma unroll
  for (int m = 1; m < 64; m <<= 1) {
    s  += __shfl_xor(s, m);
    ss += __shfl_xor(ss, m);
  }
  __shared__ float red[8];
  if ((t & 63) == 0) { red[t >> 6] = s; red[4 + (t >> 6)] = ss; }
  __syncthreads();
  s  = red[0] + red[1] + red[2] + red[3];
  ss = red[4] + red[5] + red[6] + red[7];
  const float mean = s * (1.0f / D_);
  float var = (ss - (float)D_ * mean * mean) * (1.0f / (D_ - 1));
  var = fmaxf(var, 0.0f);
  const float inv = 1.0f / (sqrtf(var) + 1e-6f);
  const float4 al = ((const float4*)alpha)[t];
  const float4 bi = ((const float4*)bias)[t];
  bf16x4 o;
  o.x = (__bf16)(al.x * (v.x - mean) * inv + bi.x);
  o.y = (__bf16)(al.y * (v.y - mean) * inv + bi.y);
  o.z = (__bf16)(al.z * (v.z - mean) * inv + bi.z);
  o.w = (__bf16)(al.w * (v.w - mean) * inv + bi.w);
  ((bf16x4*)(xn2 + base))[t] = o;
}

// ---------------------------------------------------------------------------
// FFN2 reduce: out = x1 + b2 + sum of 4 bf16 partials (contiguous at pp).
// ---------------------------------------------------------------------------
__global__ __launch_bounds__(256) void ffn2_reduce(
    const float* __restrict__ x1, const __bf16* __restrict__ pp,
    const float* __restrict__ b2, float* __restrict__ out)
{
  const int idx4 = blockIdx.x * 256 + threadIdx.x;
  float4 v = ((const float4*)x1)[idx4];
  const float4 bs = ((const float4*)b2)[idx4 & 255];
  const size_t st = (size_t)NTOK * D_ / 4;
  const bf16x4 q0 = ((const bf16x4*)pp)[idx4];
  const bf16x4 q1 = ((const bf16x4*)pp)[idx4 + st];
  const bf16x4 q2 = ((const bf16x4*)pp)[idx4 + 2 * st];
  const bf16x4 q3 = ((const bf16x4*)pp)[idx4 + 3 * st];
  v.x += bs.x + (float)q0[0] + (float)q1[0] + (float)q2[0] + (float)q3[0];
  v.y += bs.y + (float)q0[1] + (float)q1[1] + (float)q2[1] + (float)q3[1];
  v.z += bs.z + (float)q0[2] + (float)q1[2] + (float)q2[2] + (float)q3[2];
  v.w += bs.w + (float)q0[3] + (float)q1[3] + (float)q2[3] + (float)q3[3];
  ((float4*)out)[idx4] = v;
}

// ---------------------------------------------------------------------------
// weight f32->bf16 casts (jobs 0-5) + fused LN1 (job 6) in one launch.
// ---------------------------------------------------------------------------
struct CastJobs {
  const float* src[6];
  __bf16* dst[6];
  int n4[6];
};

__global__ __launch_bounds__(256) void cast_ln_kernel(
    CastJobs cj, const float* __restrict__ x, const float* __restrict__ alpha,
    const float* __restrict__ bias, __bf16* __restrict__ xn1)
{
  const int j = blockIdx.y;
  if (j < 6) {
    const int i = blockIdx.x * 256 + threadIdx.x;
    if (i < cj.n4[j]) {
      float4 v = ((const float4*)cj.src[j])[i];
      bf16x4 o;
      o.x = (__bf16)v.x; o.y = (__bf16)v.y; o.z = (__bf16)v.z; o.w = (__bf16)v.w;
      ((bf16x4*)cj.dst[j])[i] = o;
    }
    return;
  }
  const int row = blockIdx.x;
  const int t = threadIdx.x;
  const float4 v = ((const float4*)(x + (size_t)row * D_))[t];
  float s  = v.x + v.y + v.z + v.w;
  float ss = v.x * v.x + v.y * v.y + v.z * v.z + v.w * v.w;
#pragma unroll
  for (int m = 1; m < 64; m <<= 1) {
    s  += __shfl_xor(s, m);
    ss += __shfl_xor(ss, m);
  }
  __shared__ float red[8];
  if ((t & 63) == 0) { red[t >> 6] = s; red[4 + (t >> 6)] = ss; }
  __syncthreads();
  s  = red[0] + red[1] + red[2] + red[3];
  ss = red[4] + red[5] + red[6] + red[7];
  const float mean = s * (1.0f / D_);
  float var = (ss - (float)D_ * mean * mean) * (1.0f / (D_ - 1));
  var = fmaxf(var, 0.0f);
  const float inv = 1.0f / (sqrtf(var) + 1e-6f);
  const float4 al = ((const float4*)alpha)[t];
  const float4 bi = ((const float4*)bias)[t];
  bf16x4 o;
  o.x = (__bf16)(al.x * (v.x - mean) * inv + bi.x);
  o.y = (__bf16)(al.y * (v.y - mean) * inv + bi.y);
  o.z = (__bf16)(al.z * (v.z - mean) * inv + bi.z);
  o.w = (__bf16)(al.w * (v.w - mean) * inv + bi.w);
  ((bf16x4*)(xn1 + (size_t)row * D_))[t] = o;
}

// ---------------------------------------------------------------------------
// flash attention, BQ=128 (unchanged this round).
// ---------------------------------------------------------------------------
__global__ __launch_bounds__(256) void attn_kernel(
    const __bf16* __restrict__ qg, const __bf16* __restrict__ kg,
    const __bf16* __restrict__ vtg, const int* __restrict__ mask,
    __bf16* __restrict__ av)
{
  __shared__ __align__(16) __bf16 Ks[64 * 64];     // 8 KB
  __shared__ __align__(16) __bf16 Vt[64 * 64];     // 8 KB
  __shared__ __align__(16) __bf16 Ps[128 * 72];    // 18 KB (Q overlay at start)

  const int t = threadIdx.x, lane = t & 63, wv = t >> 6;
  const int l15 = lane & 15, q4 = lane >> 4;
  const int bh = blockIdx.x;
  const int b = bh >> 4, h = bh & (H_ - 1);
  const int q0 = blockIdx.y * 128;

  const int srow = lane & 7, sc8 = lane >> 3;
  const __bf16* qg0 = qg + (size_t)(b * S_ + q0 + 32 * wv + srow) * D_ + h * DK_ + sc8 * 8;
  __bf16* lQ = Ps + wv * 2304;
#pragma unroll
  for (int p = 0; p < 4; ++p)
    ld16(qg0 + (size_t)(8 * p) * D_, lQ + 512 * p);

  const __bf16* kg0 = kg + (size_t)(b * S_ + 16 * wv + srow) * D_ + h * DK_ + sc8 * 8;
  const __bf16* vt0 = vtg + (size_t)(bh * DK_ + 16 * wv + srow) * S_ + sc8 * 8;

  const int fb = ((l15 >> 3) << 9) + (q4 << 6) + ((l15 & 7) << 3);
  const int mrow = b * S_;

  float lsum[2] = {0.0f, 0.0f};
  f32x4 oacc[2][4];
#pragma unroll
  for (int m = 0; m < 2; ++m)
#pragma unroll
    for (int jd = 0; jd < 4; ++jd) oacc[m][jd] = (f32x4){0.f, 0.f, 0.f, 0.f};
  bf16x8 bq[2][2];

  for (int kv0 = 0; kv0 < S_; kv0 += 64) {
    ld16(kg0 + (size_t)kv0 * D_,       Ks + wv * 1024);
    ld16(kg0 + (size_t)(kv0 + 8) * D_, Ks + wv * 1024 + 512);
    ld16(vt0 + kv0,                    Vt + wv * 1024);
    ld16(vt0 + (size_t)8 * S_ + kv0,   Vt + wv * 1024 + 512);
    const int mv = mask[mrow + kv0 + lane];
    const bool dirty = (__ballot(mv == 0) != 0ull);
    __syncthreads();

    if (kv0 == 0) {
#pragma unroll
      for (int j = 0; j < 2; ++j)
#pragma unroll
        for (int s = 0; s < 2; ++s)
          bq[j][s] = *(const bf16x8*)(lQ + j * 1024 + s * 256 + fb);
    }

    f32x4 sacc[4][2];
#pragma unroll
    for (int i = 0; i < 4; ++i)
#pragma unroll
      for (int j = 0; j < 2; ++j) sacc[i][j] = (f32x4){0.f, 0.f, 0.f, 0.f};
#pragma unroll
    for (int i = 0; i < 4; ++i)
#pragma unroll
      for (int s = 0; s < 2; ++s) {
        bf16x8 ak = *(const bf16x8*)(Ks + i * 1024 + fb + s * 256);
#pragma unroll
        for (int j = 0; j < 2; ++j)
          sacc[i][j] = __builtin_amdgcn_mfma_f32_16x16x32_bf16(ak, bq[j][s], sacc[i][j], 0, 0, 0);
      }

    if (dirty) {
#pragma unroll
      for (int i = 0; i < 4; ++i)
#pragma unroll
        for (int r = 0; r < 4; ++r)
          if (mask[mrow + kv0 + 16 * i + 4 * q4 + r] == 0) {
            sacc[i][0][r] = -1e30f;
            sacc[i][1][r] = -1e30f;
          }
    }

#pragma unroll
    for (int j = 0; j < 2; ++j) {
      float rs = 0.0f;
#pragma unroll
      for (int i = 0; i < 4; ++i) {
        bf16x4 pb;
#pragma unroll
        for (int r = 0; r < 4; ++r) {
          float pp = EXP2(sacc[i][j][r]);
          rs += pp;
          pb[r] = (__bf16)pp;
        }
        *(bf16x4*)(Ps + (wv * 32 + j * 16 + l15) * 72 + 16 * i + q4 * 4) = pb;
      }
      lsum[j] += rs;
    }

    bf16x8 ap[2][2];
#pragma unroll
    for (int m = 0; m < 2; ++m)
#pragma unroll
      for (int s = 0; s < 2; ++s)
        ap[m][s] = *(const bf16x8*)(Ps + (wv * 32 + 16 * m + l15) * 72 + s * 32 + q4 * 8);
#pragma unroll
    for (int jd = 0; jd < 4; ++jd)
#pragma unroll
      for (int s = 0; s < 2; ++s) {
        bf16x8 bv = *(const bf16x8*)(Vt + jd * 1024 + fb + s * 256);
#pragma unroll
        for (int m = 0; m < 2; ++m)
          oacc[m][jd] = __builtin_amdgcn_mfma_f32_16x16x32_bf16(ap[m][s], bv, oacc[m][jd], 0, 0, 0);
      }
    __syncthreads();
  }

#pragma unroll
  for (int j = 0; j < 2; ++j) {
    lsum[j] += __shfl_xor(lsum[j], 16);
    lsum[j] += __shfl_xor(lsum[j], 32);
  }
  float lt[2][4];
#pragma unroll
  for (int m = 0; m < 2; ++m)
#pragma unroll
    for (int r = 0; r < 4; ++r) lt[m][r] = 1.0f / __shfl(lsum[m], q4 * 4 + r);
#pragma unroll
  for (int m = 0; m < 2; ++m)
#pragma unroll
    for (int jd = 0; jd < 4; ++jd)
#pragma unroll
      for (int r = 0; r < 4; ++r) {
        int tok = b * S_ + q0 + wv * 32 + 16 * m + q4 * 4 + r;
        int c   = h * DK_ + jd * 16 + l15;
        av[(size_t)tok * D_ + c] = (__bf16)(oacc[m][jd][r] * lt[m][r]);
      }
}

// ---------------------------------------------------------------------------
extern "C" void kernel_launch(void* const* d_in, const int* in_sizes, int n_in,
                              void* d_out, int out_size, void* d_ws, size_t ws_size,
                              hipStream_t stream) {
  const float* x      = (const float*)d_in[0];
  const int*   mask   = (const int*)d_in[1];
  const float* wq     = (const float*)d_in[2];
  const float* wk     = (const float*)d_in[3];
  const float* wv     = (const float*)d_in[4];
  const float* wo     = (const float*)d_in[5];
  const float* w1     = (const float*)d_in[6];
  const float* b1     = (const float*)d_in[7];
  const float* w2     = (const float*)d_in[8];
  const float* b2     = (const float*)d_in[9];
  const float* alpha1 = (const float*)d_in[10];
  const float* bias1  = (const float*)d_in[11];
  const float* alpha2 = (const float*)d_in[12];
  const float* bias2  = (const float*)d_in[13];

  char* ws = (char*)d_ws;
  __bf16* wqb = (__bf16*)(ws + ((size_t)0 << 20));
  __bf16* wkb = (__bf16*)(ws + ((size_t)2 << 20));
  __bf16* wvb = (__bf16*)(ws + ((size_t)4 << 20));
  __bf16* wob = (__bf16*)(ws + ((size_t)6 << 20));
  __bf16* w1b = (__bf16*)(ws + ((size_t)8 << 20));
  __bf16* w2b = (__bf16*)(ws + ((size_t)16 << 20));
  __bf16* xn1 = (__bf16*)(ws + ((size_t)24 << 20));
  __bf16* qb  = (__bf16*)(ws + ((size_t)32 << 20));
  __bf16* kb  = (__bf16*)(ws + ((size_t)40 << 20));
  __bf16* vtb = (__bf16*)(ws + ((size_t)48 << 20));
  __bf16* avb = (__bf16*)(ws + ((size_t)56 << 20));
  float*  x1  = (float*) (ws + ((size_t)64 << 20));
  __bf16* xn2 = (__bf16*)(ws + ((size_t)56 << 20));   // over avb (consumed)
  __bf16* hb  = (__bf16*)(ws + ((size_t)24 << 20));   // over xn1/op0 head
  float*  op0 = (float*) (ws + ((size_t)24 << 20));
  float*  op1 = (float*) (ws + ((size_t)40 << 20));
  // FFN2 partials: 4 x 8MB contiguous at 32..64MB (qb/op1/vtb/xn2 all dead
  // by the time gemm_ffn2_sk4 runs; stream-ordered).
  __bf16* fpp = (__bf16*)(ws + ((size_t)32 << 20));

  CastJobs cj;
  cj.src[0] = wq; cj.dst[0] = wqb; cj.n4[0] = D_ * D_ / 4;
  cj.src[1] = wk; cj.dst[1] = wkb; cj.n4[1] = D_ * D_ / 4;
  cj.src[2] = wv; cj.dst[2] = wvb; cj.n4[2] = D_ * D_ / 4;
  cj.src[3] = wo; cj.dst[3] = wob; cj.n4[3] = D_ * D_ / 4;
  cj.src[4] = w1; cj.dst[4] = w1b; cj.n4[4] = DFF_ * D_ / 4;
  cj.src[5] = w2; cj.dst[5] = w2b; cj.n4[5] = DFF_ * D_ / 4;

  cast_ln_kernel<<<dim3(DFF_ * D_ / 4 / 256, 7), 256, 0, stream>>>(
      cj, x, alpha1, bias1, xn1);

  gemm_qkv_256<<<dim3(D_ / 256, NTOK / 256, 3), 512, 0, stream>>>(
      xn1, wqb, wkb, wvb, qb, kb, vtb);

  attn_kernel<<<dim3(B_ * H_, S_ / 128), 256, 0, stream>>>(qb, kb, vtb, mask, avb);

  gemm_splitk_f32<<<dim3(D_ / 128, NTOK / 128, 2), 256, 0, stream>>>(
      avb, wob, D_, D_ / 2, op0);

  oproj_ln_reduce<<<dim3(NTOK), 256, 0, stream>>>(
      x, op0, op1, alpha2, bias2, x1, xn2);

  gemm_ffn1_256<<<dim3(DFF_ / 256, NTOK / 256), 512, 0, stream>>>(
      xn2, w1b, hb, b1);

  gemm_ffn2_sk4<<<dim3(D_ / 256, NTOK / 256, 4), 512, 0, stream>>>(
      hb, w2b, fpp);

  ffn2_reduce<<<dim3(NTOK * D_ / 4 / 256), 256, 0, stream>>>(
      x1, fpp, b2, (float*)d_out);
}

// Round 2
// 326.088 us; speedup vs baseline: 1.2679x; 1.0205x over previous
//
#include <hip/hip_runtime.h>

#define B_   2
#define S_   2048
#define D_   1024
#define H_   16
#define DK_  64
#define DFF_ 4096
#define NTOK (B_ * S_)   // 4096

#define QSCALE 0.18033688011112042f   // 0.125 * log2(e)

typedef __bf16 bf16x8 __attribute__((ext_vector_type(8)));
typedef __bf16 bf16x4 __attribute__((ext_vector_type(4)));
typedef float  f32x4  __attribute__((ext_vector_type(4)));

#if __has_builtin(__builtin_amdgcn_exp2f)
#define EXP2(x) __builtin_amdgcn_exp2f(x)
#else
#define EXP2(x) exp2f(x)
#endif

// async global->LDS 16B copy. LDS dest is wave-uniform base + lane*16.
__device__ __forceinline__ void ld16(const __bf16* g, __bf16* l) {
  __builtin_amdgcn_global_load_lds(
      (const __attribute__((address_space(1))) void*)g,
      (__attribute__((address_space(3))) void*)l, 16, 0, 0);
}

// raw barrier: NO implicit vmcnt(0) drain (that drain was the 83% stall).
// memory clobber pins all memory ops (ds_read/gload_lds) within their phase.
#define RAW_BAR()     __asm__ __volatile__("s_barrier" ::: "memory")
#define SCHED_FENCE() __builtin_amdgcn_sched_barrier(0)

// ---------------------------------------------------------------------------
// XCD-aware block swizzle for 256-thread 128^2-tile kernels (O-proj splitk).
// ---------------------------------------------------------------------------
__device__ __forceinline__ void xcd_swizzle(int& bx, int& by) {
  const int gx = gridDim.x;
  const int flat = blockIdx.y * gx + blockIdx.x;
  const int x = flat & 7;
  const int n = flat >> 3;
  if (gx == 32) {
    const int px = (x & 1) << 4, py = (x >> 1) << 3;
    const int g = n >> 5, rem = n & 31;
    bx = px + (g << 2) + (rem & 3);
    by = py + (rem >> 2);
  } else {
    const int g = n >> 4, rem = n & 15;
    bx = (g << 2) + (rem & 3);
    by = (x << 2) + (rem >> 2);
  }
}

// XCD swizzle for 256^2-tile kernels. gy==16 in all uses.
__device__ __forceinline__ void xcd_swz256(int& bx, int& by) {
  const int gx = gridDim.x;
  const int flat = blockIdx.y * gx + blockIdx.x;
  const int x = flat & 7, n = flat >> 3;
  if (gx == 16) { by = ((x >> 1) << 2) + (n >> 3); bx = ((x & 1) << 3) + (n & 7); }
  else          { by = (x << 1) + (n >> 2);        bx = n & 3; }
}

// ---------------------------------------------------------------------------
// 256^2 8-phase GEMM core (guide T1+T2+T3+T4+T5). See round-1 notes; phase
// table and hazard proof unchanged.
// ---------------------------------------------------------------------------
__device__ __forceinline__ void lda4(bf16x8 (&afr)[4], const __bf16* hb,
                                     int abase, int f0) {
#pragma unroll
  for (int i = 0; i < 4; ++i)
    afr[i] = *(const bf16x8*)(hb + abase + (f0 + i) * 512);
}

__device__ __forceinline__ void ldb4(bf16x8 (&bfr)[4], const __bf16* hb,
                                     int bbase) {
#pragma unroll
  for (int j = 0; j < 4; ++j)
    bfr[j] = *(const bf16x8*)(hb + bbase + j * 512);
}

__device__ __forceinline__ void mm16(f32x4 (&acc)[8][4], const bf16x8 (&afr)[4],
                                     const bf16x8 (&bfr)[4], int r0) {
#pragma unroll
  for (int i = 0; i < 4; ++i)
#pragma unroll
    for (int j = 0; j < 4; ++j)
      acc[r0 + i][j] =
          __builtin_amdgcn_mfma_f32_16x16x32_bf16(afr[i], bfr[j], acc[r0 + i][j], 0, 0, 0);
}

__device__ __forceinline__ void gemm_core_256(
    const __bf16* __restrict__ A, const __bf16* __restrict__ W,
    int ld, int kLen, int rowA0, int rowW0,
    f32x4 (&acc)[8][4], __bf16* Ls)
{
  const int t = threadIdx.x;
  const int lane = t & 63, wv = t >> 6;
  const int wm = wv >> 2, wn = wv & 3;
  const int l15 = lane & 15, q4 = lane >> 4;

  const int lane_rd = l15 * 32 + ((q4 * 8) ^ (((l15 >> 1) & 3) << 3));
  const int abase = wm * 4096 + lane_rd;   // + fr*512
  const int bbase = wn * 2048 + lane_rd;   // + fc*512

  const int sc0 = t ^ ((t >> 3) & 3);      // inverse-swizzled stage source
  const __bf16* gA0 = A + (size_t)(rowA0 + (sc0 >> 2)) * ld + (sc0 & 3) * 8;
  const __bf16* gA1 = gA0 + (size_t)128 * ld;
  const __bf16* gW0 = W + (size_t)(rowW0 + (sc0 >> 2)) * ld + (sc0 & 3) * 8;
  const __bf16* gW1 = gW0 + (size_t)128 * ld;
  const int d0 = wv * 512, d1 = 4096 + wv * 512;   // linear LDS dests

#pragma unroll
  for (int i = 0; i < 8; ++i)
#pragma unroll
    for (int j = 0; j < 4; ++j) acc[i][j] = (f32x4){0.f, 0.f, 0.f, 0.f};

#define HBASE(slot, mat, h) (Ls + ((((slot)*2) + (mat)) * 2 + (h)) * 8192)
#define STG_A(tt, h, slot) do { __bf16* _d = HBASE(slot, 0, h);              \
    const int _ko = (tt) * 64 + (h) * 32;                                    \
    ld16(gA0 + _ko, _d + d0); ld16(gA1 + _ko, _d + d1); } while (0)
#define STG_B(tt, h, slot) do { __bf16* _d = HBASE(slot, 1, h);              \
    const int _ko = (tt) * 64 + (h) * 32;                                    \
    ld16(gW0 + _ko, _d + d0); ld16(gW1 + _ko, _d + d1); } while (0)
#define MFMA_PH(r0) do { RAW_BAR(); SCHED_FENCE();                           \
    __builtin_amdgcn_s_setprio(1); mm16(acc, afr, bfr, r0);                  \
    __builtin_amdgcn_s_setprio(0); SCHED_FENCE(); RAW_BAR(); } while (0)

  const int NT = kLen >> 6;
  bf16x8 afr[4], bfr[4];

  STG_A(0, 0, 0); STG_A(0, 1, 0); STG_B(0, 0, 0); STG_B(0, 1, 0);
  STG_B(1, 0, 1); STG_A(1, 0, 1); STG_B(1, 1, 1);
  __asm__ __volatile__("s_waitcnt vmcnt(6)" ::: "memory");
  RAW_BAR(); SCHED_FENCE();

  for (int u = 0; u < NT; u += 2) {
    const bool g2 = (u + 2) < NT, g3 = (u + 3) < NT;
    // ph1
    lda4(afr, HBASE(0, 0, 0), abase, 0); ldb4(bfr, HBASE(0, 1, 0), bbase);
    STG_A(u + 1, 1, 1);
    MFMA_PH(0);
    // ph2
    lda4(afr, HBASE(0, 0, 0), abase, 4);
    if (g2) STG_B(u + 2, 0, 0);
    MFMA_PH(4);
    // ph3
    lda4(afr, HBASE(0, 0, 1), abase, 0); ldb4(bfr, HBASE(0, 1, 1), bbase);
    if (g2) STG_A(u + 2, 0, 0);
    MFMA_PH(0);
    // ph4
    lda4(afr, HBASE(0, 0, 1), abase, 4);
    if (g2) {
      STG_B(u + 2, 1, 0);
      __asm__ __volatile__("s_waitcnt vmcnt(6)" ::: "memory");
    } else {
      __asm__ __volatile__("s_waitcnt vmcnt(0)" ::: "memory");  // tail drain
    }
    MFMA_PH(4);
    // ph5
    lda4(afr, HBASE(1, 0, 0), abase, 0); ldb4(bfr, HBASE(1, 1, 0), bbase);
    if (g2) STG_A(u + 2, 1, 0);
    MFMA_PH(0);
    // ph6
    lda4(afr, HBASE(1, 0, 0), abase, 4);
    if (g3) STG_B(u + 3, 0, 1);
    MFMA_PH(4);
    // ph7
    lda4(afr, HBASE(1, 0, 1), abase, 0); ldb4(bfr, HBASE(1, 1, 1), bbase);
    if (g3) STG_A(u + 3, 0, 1);
    MFMA_PH(0);
    // ph8
    lda4(afr, HBASE(1, 0, 1), abase, 4);
    if (g3) STG_B(u + 3, 1, 1);
    __asm__ __volatile__("s_waitcnt vmcnt(6)" ::: "memory");
    MFMA_PH(4);
  }
#undef HBASE
#undef STG_A
#undef STG_B
#undef MFMA_PH
}

// ---------------------------------------------------------------------------
// 128^2 GEMM core (old structure) — kept for O-proj split-K only.
// ---------------------------------------------------------------------------
__device__ __forceinline__ void gemm_core_128(
    const __bf16* __restrict__ A, const __bf16* __restrict__ W,
    int ld, int kLen, int rowA0, int rowW0,
    f32x4 (&acc)[4][4], __bf16* As, __bf16* Bs)
{
  const int t    = threadIdx.x;
  const int lane = t & 63;
  const int wv   = t >> 6;
  const int wm   = (wv >> 1) << 6;
  const int wn   = (wv & 1) << 6;
  const int l15  = lane & 15;
  const int q4   = lane >> 4;

#pragma unroll
  for (int i = 0; i < 4; ++i)
#pragma unroll
    for (int j = 0; j < 4; ++j)
      acc[i][j] = (f32x4){0.f, 0.f, 0.f, 0.f};

  const __bf16* gA = A + (size_t)(rowA0 + 32 * wv + l15) * ld + q4 * 8;
  const __bf16* gW = W + (size_t)(rowW0 + 32 * wv + l15) * ld + q4 * 8;
  __bf16* lA = As + wv * 2048;
  __bf16* lB = Bs + wv * 2048;
  const size_t r16 = (size_t)16 * ld;

  const int fbg = (q4 << 7) + (l15 << 3);
  const int ia = (wm >> 4);
  const int ib = (wn >> 4);

  for (int k0 = 0; k0 < kLen; k0 += 64) {
    ld16(gA + k0,            lA);
    ld16(gA + k0 + 32,       lA + 512);
    ld16(gA + k0 + r16,      lA + 1024);
    ld16(gA + k0 + r16 + 32, lA + 1536);
    ld16(gW + k0,            lB);
    ld16(gW + k0 + 32,       lB + 512);
    ld16(gW + k0 + r16,      lB + 1024);
    ld16(gW + k0 + r16 + 32, lB + 1536);
    __syncthreads();
#pragma unroll
    for (int s = 0; s < 2; ++s) {
      bf16x8 af[4], bw[4];
#pragma unroll
      for (int i = 0; i < 4; ++i)
        af[i] = *(const bf16x8*)(As + (ia + i) * 1024 + s * 512 + fbg);
#pragma unroll
      for (int j = 0; j < 4; ++j)
        bw[j] = *(const bf16x8*)(Bs + (ib + j) * 1024 + s * 512 + fbg);
#pragma unroll
      for (int i = 0; i < 4; ++i)
#pragma unroll
        for (int j = 0; j < 4; ++j)
          acc[i][j] = __builtin_amdgcn_mfma_f32_16x16x32_bf16(af[i], bw[j], acc[i][j], 0, 0, 0);
    }
    __syncthreads();
  }
}

// ---------------------------------------------------------------------------
// QKV on the 256^2 core: grid (4,16,3). Q pre-scaled; V stored transposed.
// ---------------------------------------------------------------------------
__global__ __launch_bounds__(512, 2) void gemm_qkv_256(
    const __bf16* __restrict__ xn,
    const __bf16* __restrict__ wqb, const __bf16* __restrict__ wkb,
    const __bf16* __restrict__ wvb,
    __bf16* __restrict__ qo, __bf16* __restrict__ ko, __bf16* __restrict__ vto)
{
  __shared__ __align__(16) __bf16 Ls[65536];   // 128 KiB
  int bx, by; xcd_swz256(bx, by);
  const __bf16* W = blockIdx.z == 0 ? wqb : (blockIdx.z == 1 ? wkb : wvb);
  f32x4 acc[8][4];
  gemm_core_256(xn, W, D_, D_, by * 256, bx * 256, acc, Ls);

  const int t = threadIdx.x, lane = t & 63, wv = t >> 6;
  const int wm = wv >> 2, wn = wv & 3;
  const int l15 = lane & 15, q4 = lane >> 4;
  const int row0 = by * 256 + wm * 128;
  const int col0 = bx * 256 + wn * 64;

  if (blockIdx.z < 2) {
    __bf16* o = blockIdx.z == 0 ? qo : ko;
    const float sc = blockIdx.z == 0 ? QSCALE : 1.0f;
#pragma unroll
    for (int fr = 0; fr < 8; ++fr)
#pragma unroll
      for (int fc = 0; fc < 4; ++fc) {
        const int col = col0 + fc * 16 + l15;
#pragma unroll
        for (int r = 0; r < 4; ++r) {
          const int row = row0 + fr * 16 + q4 * 4 + r;
          o[(size_t)row * D_ + col] = (__bf16)(acc[fr][fc][r] * sc);
        }
      }
  } else {
#pragma unroll
    for (int fr = 0; fr < 8; ++fr)
#pragma unroll
      for (int fc = 0; fc < 4; ++fc) {
        const int tok0 = row0 + fr * 16 + q4 * 4;
        const int c    = col0 + fc * 16 + l15;
        const int b0 = tok0 >> 11, s0 = tok0 & (S_ - 1);
        const int hh = c >> 6, dd = c & (DK_ - 1);
        bf16x4 pk;
#pragma unroll
        for (int r = 0; r < 4; ++r) pk[r] = (__bf16)acc[fr][fc][r];
        *(bf16x4*)&vto[(size_t)((b0 * H_ + hh) * DK_ + dd) * S_ + s0] = pk;
      }
  }
}

// ---------------------------------------------------------------------------
// FFN1 on the 256^2 core: h = relu(A @ W1^T + b1). grid (16,16).
// ---------------------------------------------------------------------------
__global__ __launch_bounds__(512, 2) void gemm_ffn1_256(
    const __bf16* __restrict__ A, const __bf16* __restrict__ W,
    __bf16* __restrict__ outb, const float* __restrict__ bias)
{
  __shared__ __align__(16) __bf16 Ls[65536];
  int bx, by; xcd_swz256(bx, by);
  f32x4 acc[8][4];
  gemm_core_256(A, W, D_, D_, by * 256, bx * 256, acc, Ls);

  const int t = threadIdx.x, lane = t & 63, wv = t >> 6;
  const int wm = wv >> 2, wn = wv & 3;
  const int l15 = lane & 15, q4 = lane >> 4;
  const int row0 = by * 256 + wm * 128;
  const int col0 = bx * 256 + wn * 64;

#pragma unroll
  for (int fr = 0; fr < 8; ++fr)
#pragma unroll
    for (int fc = 0; fc < 4; ++fc) {
      const int col = col0 + fc * 16 + l15;
      const float bs = bias[col];
#pragma unroll
      for (int r = 0; r < 4; ++r) {
        const int row = row0 + fr * 16 + q4 * 4 + r;
        outb[(size_t)row * DFF_ + col] = (__bf16)fmaxf(acc[fr][fc][r] + bs, 0.0f);
      }
    }
}

// ---------------------------------------------------------------------------
// FFN2 on the 256^2 core, split-K=4: grid (4,16,4), bf16 partials contiguous.
// ---------------------------------------------------------------------------
__global__ __launch_bounds__(512, 2) void gemm_ffn2_sk4(
    const __bf16* __restrict__ A, const __bf16* __restrict__ W,
    __bf16* __restrict__ pp)
{
  __shared__ __align__(16) __bf16 Ls[65536];
  int bx, by; xcd_swz256(bx, by);
  const int z = blockIdx.z;
  f32x4 acc[8][4];
  gemm_core_256(A + (size_t)z * 1024, W + (size_t)z * 1024, DFF_, 1024,
                by * 256, bx * 256, acc, Ls);

  const int t = threadIdx.x, lane = t & 63, wv = t >> 6;
  const int wm = wv >> 2, wn = wv & 3;
  const int l15 = lane & 15, q4 = lane >> 4;
  const int row0 = by * 256 + wm * 128;
  const int col0 = bx * 256 + wn * 64;
  __bf16* out = pp + (size_t)z * NTOK * D_;

#pragma unroll
  for (int fr = 0; fr < 8; ++fr)
#pragma unroll
    for (int fc = 0; fc < 4; ++fc) {
      const int col = col0 + fc * 16 + l15;
#pragma unroll
      for (int r = 0; r < 4; ++r) {
        const int row = row0 + fr * 16 + q4 * 4 + r;
        out[(size_t)row * D_ + col] = (__bf16)acc[fr][fc][r];
      }
    }
}

// ---------------------------------------------------------------------------
// O-proj split-K GEMM partials (old 128^2 core). grid (8, 32, 2).
// ---------------------------------------------------------------------------
__global__ __launch_bounds__(256) void gemm_splitk_f32(
    const __bf16* __restrict__ A, const __bf16* __restrict__ W,
    int K, int kPart, float* __restrict__ pp)
{
  __shared__ __align__(16) __bf16 As[128 * 64];
  __shared__ __align__(16) __bf16 Bs[128 * 64];
  int bx, by; xcd_swizzle(bx, by);
  f32x4 acc[4][4];
  const int z = blockIdx.z;
  gemm_core_128(A + (size_t)z * kPart, W + (size_t)z * kPart, K, kPart,
                by * 128, bx * 128, acc, As, Bs);

  const int t = threadIdx.x, lane = t & 63, wv = t >> 6;
  const int wm = (wv >> 1) << 6, wn = (wv & 1) << 6;
  const int l15 = lane & 15, q4 = lane >> 4;
  const int row0 = by * 128 + wm;
  const int col0 = bx * 128 + wn;
  float* out = pp + (size_t)z * NTOK * D_;

#pragma unroll
  for (int i = 0; i < 4; ++i)
#pragma unroll
    for (int j = 0; j < 4; ++j)
#pragma unroll
      for (int r = 0; r < 4; ++r) {
        int row = row0 + 16 * i + q4 * 4 + r;
        int col = col0 + 16 * j + l15;
        out[(size_t)row * D_ + col] = acc[i][j][r];
      }
}

// ---------------------------------------------------------------------------
// O-proj reduce + LN2 fused: x1 = x + p0 + p1; xn2 = LN(x1). 1 block/row.
// ---------------------------------------------------------------------------
__global__ __launch_bounds__(256) void oproj_ln_reduce(
    const float* __restrict__ x, const float* __restrict__ p0,
    const float* __restrict__ p1, const float* __restrict__ alpha,
    const float* __restrict__ bias, float* __restrict__ x1,
    __bf16* __restrict__ xn2)
{
  const int row = blockIdx.x;
  const int t = threadIdx.x;
  const size_t base = (size_t)row * D_;
  float4 v  = ((const float4*)(x  + base))[t];
  const float4 a0 = ((const float4*)(p0 + base))[t];
  const float4 a1 = ((const float4*)(p1 + base))[t];
  v.x += a0.x + a1.x; v.y += a0.y + a1.y;
  v.z += a0.z + a1.z; v.w += a0.w + a1.w;
  ((float4*)(x1 + base))[t] = v;

  float s  = v.x + v.y + v.z + v.w;
  float ss = v.x * v.x + v.y * v.y + v.z * v.z + v.w * v.w;
#pragma unroll
  for (int m = 1; m < 64; m <<= 1) {
    s  += __shfl_xor(s, m);
    ss += __shfl_xor(ss, m);
  }
  __shared__ float red[8];
  if ((t & 63) == 0) { red[t >> 6] = s; red[4 + (t >> 6)] = ss; }
  __syncthreads();
  s  = red[0] + red[1] + red[2] + red[3];
  ss = red[4] + red[5] + red[6] + red[7];
  const float mean = s * (1.0f / D_);
  float var = (ss - (float)D_ * mean * mean) * (1.0f / (D_ - 1));
  var = fmaxf(var, 0.0f);
  const float inv = 1.0f / (sqrtf(var) + 1e-6f);
  const float4 al = ((const float4*)alpha)[t];
  const float4 bi = ((const float4*)bias)[t];
  bf16x4 o;
  o.x = (__bf16)(al.x * (v.x - mean) * inv + bi.x);
  o.y = (__bf16)(al.y * (v.y - mean) * inv + bi.y);
  o.z = (__bf16)(al.z * (v.z - mean) * inv + bi.z);
  o.w = (__bf16)(al.w * (v.w - mean) * inv + bi.w);
  ((bf16x4*)(xn2 + base))[t] = o;
}

// ---------------------------------------------------------------------------
// FFN2 reduce: out = x1 + b2 + sum of 4 bf16 partials (contiguous at pp).
// ---------------------------------------------------------------------------
__global__ __launch_bounds__(256) void ffn2_reduce(
    const float* __restrict__ x1, const __bf16* __restrict__ pp,
    const float* __restrict__ b2, float* __restrict__ out)
{
  const int idx4 = blockIdx.x * 256 + threadIdx.x;
  float4 v = ((const float4*)x1)[idx4];
  const float4 bs = ((const float4*)b2)[idx4 & 255];
  const size_t st = (size_t)NTOK * D_ / 4;
  const bf16x4 q0 = ((const bf16x4*)pp)[idx4];
  const bf16x4 q1 = ((const bf16x4*)pp)[idx4 + st];
  const bf16x4 q2 = ((const bf16x4*)pp)[idx4 + 2 * st];
  const bf16x4 q3 = ((const bf16x4*)pp)[idx4 + 3 * st];
  v.x += bs.x + (float)q0[0] + (float)q1[0] + (float)q2[0] + (float)q3[0];
  v.y += bs.y + (float)q0[1] + (float)q1[1] + (float)q2[1] + (float)q3[1];
  v.z += bs.z + (float)q0[2] + (float)q1[2] + (float)q2[2] + (float)q3[2];
  v.w += bs.w + (float)q0[3] + (float)q1[3] + (float)q2[3] + (float)q3[3];
  ((float4*)out)[idx4] = v;
}

// ---------------------------------------------------------------------------
// weight f32->bf16 casts (jobs 0-5) + fused LN1 (job 6) in one launch.
// ---------------------------------------------------------------------------
struct CastJobs {
  const float* src[6];
  __bf16* dst[6];
  int n4[6];
};

__global__ __launch_bounds__(256) void cast_ln_kernel(
    CastJobs cj, const float* __restrict__ x, const float* __restrict__ alpha,
    const float* __restrict__ bias, __bf16* __restrict__ xn1)
{
  const int j = blockIdx.y;
  if (j < 6) {
    const int i = blockIdx.x * 256 + threadIdx.x;
    if (i < cj.n4[j]) {
      float4 v = ((const float4*)cj.src[j])[i];
      bf16x4 o;
      o.x = (__bf16)v.x; o.y = (__bf16)v.y; o.z = (__bf16)v.z; o.w = (__bf16)v.w;
      ((bf16x4*)cj.dst[j])[i] = o;
    }
    return;
  }
  const int row = blockIdx.x;
  const int t = threadIdx.x;
  const float4 v = ((const float4*)(x + (size_t)row * D_))[t];
  float s  = v.x + v.y + v.z + v.w;
  float ss = v.x * v.x + v.y * v.y + v.z * v.z + v.w * v.w;
#pragma unroll
  for (int m = 1; m < 64; m <<= 1) {
    s  += __shfl_xor(s, m);
    ss += __shfl_xor(ss, m);
  }
  __shared__ float red[8];
  if ((t & 63) == 0) { red[t >> 6] = s; red[4 + (t >> 6)] = ss; }
  __syncthreads();
  s  = red[0] + red[1] + red[2] + red[3];
  ss = red[4] + red[5] + red[6] + red[7];
  const float mean = s * (1.0f / D_);
  float var = (ss - (float)D_ * mean * mean) * (1.0f / (D_ - 1));
  var = fmaxf(var, 0.0f);
  const float inv = 1.0f / (sqrtf(var) + 1e-6f);
  const float4 al = ((const float4*)alpha)[t];
  const float4 bi = ((const float4*)bias)[t];
  bf16x4 o;
  o.x = (__bf16)(al.x * (v.x - mean) * inv + bi.x);
  o.y = (__bf16)(al.y * (v.y - mean) * inv + bi.y);
  o.z = (__bf16)(al.z * (v.z - mean) * inv + bi.z);
  o.w = (__bf16)(al.w * (v.w - mean) * inv + bi.w);
  ((bf16x4*)(xn1 + (size_t)row * D_))[t] = o;
}

// ---------------------------------------------------------------------------
// flash attention, BQ=128, R2: K/V double-buffered (prefetch next kv-tile at
// iteration top -> global->LDS latency hides under QK/softmax/PV), ONE
// __syncthreads per iter (its vmcnt(0) drain is harmless: loads had the whole
// iteration to land). Mask hoisted to a one-time scan into per-chunk dirty
// flags (removes per-iter global load + ballot from the critical path; cold
// path unchanged for general masks). setprio around MFMA clusters (T5).
// LDS = 16K(Ks dbuf)+16K(Vt dbuf)+18K(Ps)+128B = 50.1 KB -> 2 blocks/CU.
// Hazards: stage targets buf^1, which end-of-prev-iter barrier proved idle
// (WAR); end-of-iter drain+barrier lands it before next iter's reads (RAW).
// ---------------------------------------------------------------------------
__global__ __launch_bounds__(256) void attn_kernel(
    const __bf16* __restrict__ qg, const __bf16* __restrict__ kg,
    const __bf16* __restrict__ vtg, const int* __restrict__ mask,
    __bf16* __restrict__ av)
{
  __shared__ __align__(16) __bf16 Ks[2][64 * 64];  // 16 KB
  __shared__ __align__(16) __bf16 Vt[2][64 * 64];  // 16 KB
  __shared__ __align__(16) __bf16 Ps[128 * 72];    // 18 KB (Q overlay at start)
  __shared__ int Dd[32];                           // per-kv-chunk dirty flags

  const int t = threadIdx.x, lane = t & 63, wv = t >> 6;
  const int l15 = lane & 15, q4 = lane >> 4;
  const int bh = blockIdx.x;
  const int b = bh >> 4, h = bh & (H_ - 1);
  const int q0 = blockIdx.y * 128;

  const int srow = lane & 7, sc8 = lane >> 3;
  const __bf16* qg0 = qg + (size_t)(b * S_ + q0 + 32 * wv + srow) * D_ + h * DK_ + sc8 * 8;
  __bf16* lQ = Ps + wv * 2304;
#pragma unroll
  for (int p = 0; p < 4; ++p)
    ld16(qg0 + (size_t)(8 * p) * D_, lQ + 512 * p);

  const __bf16* kg0 = kg + (size_t)(b * S_ + 16 * wv + srow) * D_ + h * DK_ + sc8 * 8;
  const __bf16* vt0 = vtg + (size_t)(bh * DK_ + 16 * wv + srow) * S_ + sc8 * 8;

  if (t < 32) Dd[t] = 0;

  // stage kv-tile 0 into buf 0
  ld16(kg0,                  Ks[0] + wv * 1024);
  ld16(kg0 + (size_t)8 * D_, Ks[0] + wv * 1024 + 512);
  ld16(vt0,                  Vt[0] + wv * 1024);
  ld16(vt0 + (size_t)8 * S_, Vt[0] + wv * 1024 + 512);

  __syncthreads();   // Dd init visible; drains Q/KV0 staging

  // one-time mask scan: thread t covers kv = 8t..8t+8 (chunk t>>3)
  {
    const int4* m4 = (const int4*)(mask + (size_t)b * S_) + t * 2;
    const int4 a = m4[0], c = m4[1];
    const bool anyz = (a.x == 0) | (a.y == 0) | (a.z == 0) | (a.w == 0) |
                      (c.x == 0) | (c.y == 0) | (c.z == 0) | (c.w == 0);
    if (anyz) Dd[t >> 3] = 1;
  }
  __syncthreads();

  const int fb = ((l15 >> 3) << 9) + (q4 << 6) + ((l15 & 7) << 3);
  const int mrow = b * S_;

  // Q B-frags from wave-private overlay (region is wave-local; Ps softmax
  // writes later hit the same wave-local rows only).
  bf16x8 bq[2][2];
#pragma unroll
  for (int j = 0; j < 2; ++j)
#pragma unroll
    for (int s = 0; s < 2; ++s)
      bq[j][s] = *(const bf16x8*)(lQ + j * 1024 + s * 256 + fb);

  float lsum[2] = {0.0f, 0.0f};
  f32x4 oacc[2][4];
#pragma unroll
  for (int m = 0; m < 2; ++m)
#pragma unroll
    for (int jd = 0; jd < 4; ++jd) oacc[m][jd] = (f32x4){0.f, 0.f, 0.f, 0.f};

  for (int kv0 = 0; kv0 < S_; kv0 += 64) {
    const int buf = (kv0 >> 6) & 1;
    // prefetch next kv-tile into buf^1 (flies under the whole compute phase)
    if (kv0 + 64 < S_) {
      const size_t nk = (size_t)(kv0 + 64);
      ld16(kg0 + nk * D_,              Ks[buf ^ 1] + wv * 1024);
      ld16(kg0 + (nk + 8) * D_,        Ks[buf ^ 1] + wv * 1024 + 512);
      ld16(vt0 + nk,                   Vt[buf ^ 1] + wv * 1024);
      ld16(vt0 + (size_t)8 * S_ + nk,  Vt[buf ^ 1] + wv * 1024 + 512);
    }

    // S^T = K Q^T : rows kv (4 i-tiles), cols q (wave's 2 j-slices of 16)
    f32x4 sacc[4][2];
#pragma unroll
    for (int i = 0; i < 4; ++i)
#pragma unroll
      for (int j = 0; j < 2; ++j) sacc[i][j] = (f32x4){0.f, 0.f, 0.f, 0.f};
    __builtin_amdgcn_s_setprio(1);
#pragma unroll
    for (int i = 0; i < 4; ++i)
#pragma unroll
      for (int s = 0; s < 2; ++s) {
        bf16x8 ak = *(const bf16x8*)(Ks[buf] + i * 1024 + fb + s * 256);
#pragma unroll
        for (int j = 0; j < 2; ++j)
          sacc[i][j] = __builtin_amdgcn_mfma_f32_16x16x32_bf16(ak, bq[j][s], sacc[i][j], 0, 0, 0);
      }
    __builtin_amdgcn_s_setprio(0);

    if (Dd[kv0 >> 6]) {   // cold path (all-ones mask never takes it)
#pragma unroll
      for (int i = 0; i < 4; ++i)
#pragma unroll
        for (int r = 0; r < 4; ++r)
          if (mask[mrow + kv0 + 16 * i + 4 * q4 + r] == 0) {
            sacc[i][0][r] = -1e30f;
            sacc[i][1][r] = -1e30f;
          }
    }

    // fixed-max softmax; P -> Ps rows q (wave-local); l-sum per-lane
#pragma unroll
    for (int j = 0; j < 2; ++j) {
      float rs = 0.0f;
#pragma unroll
      for (int i = 0; i < 4; ++i) {
        bf16x4 pb;
#pragma unroll
        for (int r = 0; r < 4; ++r) {
          float pp = EXP2(sacc[i][j][r]);
          rs += pp;
          pb[r] = (__bf16)pp;
        }
        *(bf16x4*)(Ps + (wv * 32 + j * 16 + l15) * 72 + 16 * i + q4 * 4) = pb;
      }
      lsum[j] += rs;
    }

    // O += P V : A = P rows q (2 m-tiles), B = V^T rows d (4 jd-tiles)
    bf16x8 ap[2][2];
#pragma unroll
    for (int m = 0; m < 2; ++m)
#pragma unroll
      for (int s = 0; s < 2; ++s)
        ap[m][s] = *(const bf16x8*)(Ps + (wv * 32 + 16 * m + l15) * 72 + s * 32 + q4 * 8);
    __builtin_amdgcn_s_setprio(1);
#pragma unroll
    for (int jd = 0; jd < 4; ++jd)
#pragma unroll
      for (int s = 0; s < 2; ++s) {
        bf16x8 bv = *(const bf16x8*)(Vt[buf] + jd * 1024 + fb + s * 256);
#pragma unroll
        for (int m = 0; m < 2; ++m)
          oacc[m][jd] = __builtin_amdgcn_mfma_f32_16x16x32_bf16(ap[m][s], bv, oacc[m][jd], 0, 0, 0);
      }
    __builtin_amdgcn_s_setprio(0);

    // single barrier per iter: drains prefetch (RAW for next iter) and
    // proves all waves done reading buf (WAR for iter+2's restage).
    __syncthreads();
  }

  // deferred l reduction across q4 groups, transpose to O-row ownership, store
#pragma unroll
  for (int j = 0; j < 2; ++j) {
    lsum[j] += __shfl_xor(lsum[j], 16);
    lsum[j] += __shfl_xor(lsum[j], 32);
  }
  float lt[2][4];
#pragma unroll
  for (int m = 0; m < 2; ++m)
#pragma unroll
    for (int r = 0; r < 4; ++r) lt[m][r] = 1.0f / __shfl(lsum[m], q4 * 4 + r);
#pragma unroll
  for (int m = 0; m < 2; ++m)
#pragma unroll
    for (int jd = 0; jd < 4; ++jd)
#pragma unroll
      for (int r = 0; r < 4; ++r) {
        int tok = b * S_ + q0 + wv * 32 + 16 * m + q4 * 4 + r;
        int c   = h * DK_ + jd * 16 + l15;
        av[(size_t)tok * D_ + c] = (__bf16)(oacc[m][jd][r] * lt[m][r]);
      }
}

// ---------------------------------------------------------------------------
extern "C" void kernel_launch(void* const* d_in, const int* in_sizes, int n_in,
                              void* d_out, int out_size, void* d_ws, size_t ws_size,
                              hipStream_t stream) {
  const float* x      = (const float*)d_in[0];
  const int*   mask   = (const int*)d_in[1];
  const float* wq     = (const float*)d_in[2];
  const float* wk     = (const float*)d_in[3];
  const float* wv     = (const float*)d_in[4];
  const float* wo     = (const float*)d_in[5];
  const float* w1     = (const float*)d_in[6];
  const float* b1     = (const float*)d_in[7];
  const float* w2     = (const float*)d_in[8];
  const float* b2     = (const float*)d_in[9];
  const float* alpha1 = (const float*)d_in[10];
  const float* bias1  = (const float*)d_in[11];
  const float* alpha2 = (const float*)d_in[12];
  const float* bias2  = (const float*)d_in[13];

  char* ws = (char*)d_ws;
  __bf16* wqb = (__bf16*)(ws + ((size_t)0 << 20));
  __bf16* wkb = (__bf16*)(ws + ((size_t)2 << 20));
  __bf16* wvb = (__bf16*)(ws + ((size_t)4 << 20));
  __bf16* wob = (__bf16*)(ws + ((size_t)6 << 20));
  __bf16* w1b = (__bf16*)(ws + ((size_t)8 << 20));
  __bf16* w2b = (__bf16*)(ws + ((size_t)16 << 20));
  __bf16* xn1 = (__bf16*)(ws + ((size_t)24 << 20));
  __bf16* qb  = (__bf16*)(ws + ((size_t)32 << 20));
  __bf16* kb  = (__bf16*)(ws + ((size_t)40 << 20));
  __bf16* vtb = (__bf16*)(ws + ((size_t)48 << 20));
  __bf16* avb = (__bf16*)(ws + ((size_t)56 << 20));
  float*  x1  = (float*) (ws + ((size_t)64 << 20));
  __bf16* xn2 = (__bf16*)(ws + ((size_t)56 << 20));   // over avb (consumed)
  __bf16* hb  = (__bf16*)(ws + ((size_t)24 << 20));   // over xn1/op0 head
  float*  op0 = (float*) (ws + ((size_t)24 << 20));
  float*  op1 = (float*) (ws + ((size_t)40 << 20));
  // FFN2 partials: 4 x 8MB contiguous at 32..64MB (qb/op1/vtb/xn2 all dead
  // by the time gemm_ffn2_sk4 runs; stream-ordered).
  __bf16* fpp = (__bf16*)(ws + ((size_t)32 << 20));

  CastJobs cj;
  cj.src[0] = wq; cj.dst[0] = wqb; cj.n4[0] = D_ * D_ / 4;
  cj.src[1] = wk; cj.dst[1] = wkb; cj.n4[1] = D_ * D_ / 4;
  cj.src[2] = wv; cj.dst[2] = wvb; cj.n4[2] = D_ * D_ / 4;
  cj.src[3] = wo; cj.dst[3] = wob; cj.n4[3] = D_ * D_ / 4;
  cj.src[4] = w1; cj.dst[4] = w1b; cj.n4[4] = DFF_ * D_ / 4;
  cj.src[5] = w2; cj.dst[5] = w2b; cj.n4[5] = DFF_ * D_ / 4;

  cast_ln_kernel<<<dim3(DFF_ * D_ / 4 / 256, 7), 256, 0, stream>>>(
      cj, x, alpha1, bias1, xn1);

  gemm_qkv_256<<<dim3(D_ / 256, NTOK / 256, 3), 512, 0, stream>>>(
      xn1, wqb, wkb, wvb, qb, kb, vtb);

  attn_kernel<<<dim3(B_ * H_, S_ / 128), 256, 0, stream>>>(qb, kb, vtb, mask, avb);

  gemm_splitk_f32<<<dim3(D_ / 128, NTOK / 128, 2), 256, 0, stream>>>(
      avb, wob, D_, D_ / 2, op0);

  oproj_ln_reduce<<<dim3(NTOK), 256, 0, stream>>>(
      x, op0, op1, alpha2, bias2, x1, xn2);

  gemm_ffn1_256<<<dim3(DFF_ / 256, NTOK / 256), 512, 0, stream>>>(
      xn2, w1b, hb, b1);

  gemm_ffn2_sk4<<<dim3(D_ / 256, NTOK / 256, 4), 512, 0, stream>>>(
      hb, w2b, fpp);

  ffn2_reduce<<<dim3(NTOK * D_ / 4 / 256), 256, 0, stream>>>(
      x1, fpp, b2, (float*)d_out);
}